// Round 1
// baseline (3277.629 us; speedup 1.0000x reference)
//
#include <hip/hip_runtime.h>

#define NCH 128
#define TN 16

// Zero the accumulated workspace regions; init out = N * b_v2 (per-node bias,
// folded analytically so head kernel only accumulates the weighted part).
__global__ void zero_kernel(float* ws, long long total, float* out,
                            const float* __restrict__ bv2, int n) {
  long long i = (long long)blockIdx.x * blockDim.x + threadIdx.x;
  if (i < total) ws[i] = 0.0f;
  if (i == 0) out[0] = (float)n * bv2[0];
}

// deg0 = out-degree (src counts), indeg = in-degree (dst counts, no self loop)
__global__ void degree_kernel(const int* __restrict__ src, const int* __restrict__ dst,
                              float* deg0, float* indeg, int ne) {
  int e = blockIdx.x * blockDim.x + threadIdx.x;
  if (e < ne) {
    atomicAdd(&deg0[src[e]], 1.0f);
    atomicAdd(&indeg[dst[e]], 1.0f);
  }
}

// p2[n] = dinv[n] * xin[n]  where xin = [x, deg0], dinv = rsqrt(indeg+1)
__global__ void p2_kernel(const float* __restrict__ x, const float* __restrict__ deg0,
                          const float* __restrict__ indeg, float* __restrict__ p2, int n) {
  int i = blockIdx.x * blockDim.x + threadIdx.x;
  if (i < n) {
    float dinv = rsqrtf(indeg[i] + 1.0f);
    p2[2 * i]     = dinv * x[i];
    p2[2 * i + 1] = dinv * deg0[i];
  }
}

// GCN aggregation in 2-dim feature space (matmul commutes with segment_sum):
// t2[d] += dinv[s]*xin[s]  for each edge. Only 2 atomics/edge.
__global__ void gcn_scatter_kernel(const int* __restrict__ src, const int* __restrict__ dst,
                                   const float* __restrict__ p2, float* __restrict__ t2, int ne) {
  int e = blockIdx.x * blockDim.x + threadIdx.x;
  if (e < ne) {
    int s = src[e], d = dst[e];
    atomicAdd(&t2[2 * d],     p2[2 * s]);
    atomicAdd(&t2[2 * d + 1], p2[2 * s + 1]);
  }
}

// a1[n][c] = relu( (dinv[n]*(t2[n]+p2[n])) . W_gcn[:,c] + b_gcn[c] )
// (p2[n] = dinv[n]*xin[n] is exactly the self-loop term before the outer dinv)
__global__ void a1_kernel(const float* __restrict__ t2, const float* __restrict__ p2,
                          const float* __restrict__ indeg, const float* __restrict__ Wg,
                          const float* __restrict__ bg, float* __restrict__ a1, int n) {
  int i = blockIdx.x * blockDim.x + threadIdx.x;
  if (i >= n * NCH) return;
  int node = i >> 7, c = i & 127;
  float dinv = rsqrtf(indeg[node] + 1.0f);
  float t0 = dinv * (t2[2 * node]     + p2[2 * node]);
  float t1 = dinv * (t2[2 * node + 1] + p2[2 * node + 1]);
  float z = fmaf(t0, Wg[c], fmaf(t1, Wg[NCH + c], bg[c]));
  a1[i] = fmaxf(z, 0.0f);
}

// SAGE neighbor sum: aggs[dst] += a1[src], 128-wide. float4 gather + 4 atomics.
__global__ void sage_scatter_kernel(const int* __restrict__ src, const int* __restrict__ dst,
                                    const float* __restrict__ a1, float* __restrict__ aggs,
                                    int ne) {
  int g = blockIdx.x * blockDim.x + threadIdx.x;
  if (g >= ne * 32) return;
  int e = g >> 5, c4 = (g & 31) << 2;
  int s = src[e], d = dst[e];
  float4 v = *reinterpret_cast<const float4*>(a1 + (size_t)s * NCH + c4);
  float* o = aggs + (size_t)d * NCH + c4;
  atomicAdd(o + 0, v.x);
  atomicAdd(o + 1, v.y);
  atomicAdd(o + 2, v.z);
  atomicAdd(o + 3, v.w);
}

// Fused: a2 = (aggs/cnt)@Wl + b_l + a1@Wr ; v = relu(a2@Wv1+bv1)@Wv2 ; sum.
// 16 nodes per 256-thread block; Wl/Wr chunks staged in LDS (reused for Wv1).
__global__ __launch_bounds__(256) void head_kernel(
    const float* __restrict__ a1, const float* __restrict__ aggs,
    const float* __restrict__ indeg,
    const float* __restrict__ Wl, const float* __restrict__ bl,
    const float* __restrict__ Wr,
    const float* __restrict__ Wv1, const float* __restrict__ bv1,
    const float* __restrict__ Wv2, float* __restrict__ out, int n) {
  __shared__ float sW[2 * 32 * NCH];  // 32 KB: Wl chunk | Wr chunk (later Wv1)
  __shared__ float sIn[2 * TN * 32];  // 4 KB: agg chunk | a1 chunk
  __shared__ float sA2[TN * NCH];     // 8 KB
  int tid = threadIdx.x;
  int node0 = blockIdx.x * TN;
  int c = tid & 127;
  int half = tid >> 7;  // which parity of node this thread covers
  float acc[TN / 2];
  float blc = bl[c];
#pragma unroll
  for (int i = 0; i < TN / 2; i++) acc[i] = blc;

  for (int k0 = 0; k0 < NCH; k0 += 32) {
    for (int t = tid; t < 32 * NCH; t += 256) {
      int kk = t >> 7, cc = t & 127;
      sW[t]            = Wl[(k0 + kk) * NCH + cc];
      sW[32 * NCH + t] = Wr[(k0 + kk) * NCH + cc];
    }
    for (int t = tid; t < TN * 32; t += 256) {
      int nn = t >> 5, kk = t & 31;
      int node = node0 + nn;
      float va = 0.0f, vb = 0.0f;
      if (node < n) {
        float inv = 1.0f / fmaxf(indeg[node], 1.0f);
        va = aggs[(size_t)node * NCH + k0 + kk] * inv;
        vb = a1[(size_t)node * NCH + k0 + kk];
      }
      sIn[t]           = va;
      sIn[TN * 32 + t] = vb;
    }
    __syncthreads();
    for (int kk = 0; kk < 32; kk++) {
      float wl = sW[kk * NCH + c];
      float wr = sW[32 * NCH + kk * NCH + c];
#pragma unroll
      for (int i = 0; i < TN / 2; i++) {
        int nn = half + 2 * i;
        acc[i] = fmaf(sIn[nn * 32 + kk], wl, acc[i]);
        acc[i] = fmaf(sIn[TN * 32 + nn * 32 + kk], wr, acc[i]);
      }
    }
    __syncthreads();
  }
#pragma unroll
  for (int i = 0; i < TN / 2; i++) sA2[(half + 2 * i) * NCH + c] = acc[i];
  // reuse sW for Wv1 [128,64] = 8192 floats (exactly sW's size)
  for (int t = tid; t < NCH * 64; t += 256) sW[t] = Wv1[t];
  __syncthreads();
  int j = tid & 63, w = tid >> 6;
  float bvj = bv1[j], w2 = Wv2[j];
  float vsum = 0.0f;
#pragma unroll
  for (int i = 0; i < TN / 4; i++) {
    int nn = w * (TN / 4) + i;
    if (node0 + nn < n) {
      float h = bvj;
      for (int cc = 0; cc < NCH; cc++)
        h = fmaf(sA2[nn * NCH + cc], sW[cc * 64 + j], h);
      vsum += fmaxf(h, 0.0f) * w2;
    }
  }
#pragma unroll
  for (int off = 32; off > 0; off >>= 1) vsum += __shfl_down(vsum, off, 64);
  if ((tid & 63) == 0) atomicAdd(out, vsum);
}

extern "C" void kernel_launch(void* const* d_in, const int* in_sizes, int n_in,
                              void* d_out, int out_size, void* d_ws, size_t ws_size,
                              hipStream_t stream) {
  const float* x   = (const float*)d_in[0];
  const int*   ei  = (const int*)d_in[1];
  const float* Wg  = (const float*)d_in[2];
  const float* bg  = (const float*)d_in[3];
  const float* Wl  = (const float*)d_in[4];
  const float* bl  = (const float*)d_in[5];
  const float* Wr  = (const float*)d_in[6];
  const float* Wv1 = (const float*)d_in[7];
  const float* bv1 = (const float*)d_in[8];
  const float* Wv2 = (const float*)d_in[9];
  const float* bv2 = (const float*)d_in[10];
  float* out = (float*)d_out;

  int n  = in_sizes[0];      // x is [N,1]
  int E_ = in_sizes[1] / 2;  // edge_index is [2,E]
  const int* src = ei;
  const int* dst = ei + E_;

  float* ws = (float*)d_ws;
  float* deg0f  = ws;                       // [n]
  float* indegf = ws + (size_t)n;           // [n]
  float* p2     = ws + 2 * (size_t)n;       // [n,2]  dinv*xin
  float* t2     = ws + 4 * (size_t)n;       // [n,2]  gcn aggregate
  float* a1buf  = ws + 6 * (size_t)n;       // [n,128]
  float* sageS  = ws + 134 * (size_t)n;     // [n,128] sage neighbor sum
  // total 262*n floats ~= 52.4 MB

  long long zt = 262LL * n;
  int zb = (int)((zt + 255) / 256);
  zero_kernel<<<zb, 256, 0, stream>>>(ws, zt, out, bv2, n);
  degree_kernel<<<(E_ + 255) / 256, 256, 0, stream>>>(src, dst, deg0f, indegf, E_);
  p2_kernel<<<(n + 255) / 256, 256, 0, stream>>>(x, deg0f, indegf, p2, n);
  gcn_scatter_kernel<<<(E_ + 255) / 256, 256, 0, stream>>>(src, dst, p2, t2, E_);
  a1_kernel<<<(n * NCH + 255) / 256, 256, 0, stream>>>(t2, p2, indegf, Wg, bg, a1buf, n);
  {
    long long tot = (long long)E_ * 32;
    int blocks = (int)((tot + 255) / 256);
    sage_scatter_kernel<<<blocks, 256, 0, stream>>>(src, dst, a1buf, sageS, E_);
  }
  head_kernel<<<(n + TN - 1) / TN, 256, 0, stream>>>(a1buf, sageS, indegf, Wl, bl, Wr,
                                                     Wv1, bv1, Wv2, out, n);
}

// Round 2
// 666.873 us; speedup vs baseline: 4.9149x; 4.9149x over previous
//
#include <hip/hip_runtime.h>

#define NCH 128
#define TN 16

// Zero histogram/counter arrays; init out = N * b_v2 (bias folded analytically).
__global__ void init_kernel(int* zi, long long total, float* out,
                            const float* __restrict__ bv2, int n) {
  long long i = (long long)blockIdx.x * blockDim.x + threadIdx.x;
  if (i < total) zi[i] = 0;
  if (i == 0) out[0] = (float)n * bv2[0];
}

// outdeg (src histogram) and indeg (dst histogram), int atomics.
__global__ void degree_kernel(const int* __restrict__ src, const int* __restrict__ dst,
                              int* outdeg, int* indeg, int ne) {
  int e = blockIdx.x * blockDim.x + threadIdx.x;
  if (e < ne) {
    atomicAdd(&outdeg[src[e]], 1);
    atomicAdd(&indeg[dst[e]], 1);
  }
}

// ---- 3-kernel exclusive scan of indeg -> row_ptr (1024 elems per block) ----
__global__ void scan1_kernel(const int* __restrict__ indeg, int* bsum, int n) {
  __shared__ int s[256];
  int b = blockIdx.x, t = threadIdx.x;
  int base = b * 1024 + t * 4;
  int v = 0;
#pragma unroll
  for (int j = 0; j < 4; j++) { int i = base + j; if (i < n) v += indeg[i]; }
  s[t] = v; __syncthreads();
  for (int off = 128; off > 0; off >>= 1) {
    if (t < off) s[t] += s[t + off];
    __syncthreads();
  }
  if (t == 0) bsum[b] = s[0];
}

__global__ void scan2_kernel(int* bsum, int nb) {  // 1 wave, nb <= 64
  int l = threadIdx.x;
  int own = (l < nb) ? bsum[l] : 0;
  int v = own;
  for (int off = 1; off < 64; off <<= 1) {
    int u = __shfl_up(v, off, 64);
    if (l >= off) v += u;
  }
  if (l < nb) bsum[l] = v - own;  // exclusive
}

__global__ void scan3_kernel(const int* __restrict__ indeg, const int* __restrict__ bsum,
                             int* row_ptr, int n, int ne) {
  __shared__ int s[256];
  int b = blockIdx.x, t = threadIdx.x;
  int base = b * 1024 + t * 4;
  int loc[4]; int v = 0;
#pragma unroll
  for (int j = 0; j < 4; j++) {
    int i = base + j;
    int d = (i < n) ? indeg[i] : 0;
    loc[j] = v; v += d;
  }
  s[t] = v; __syncthreads();
  for (int off = 1; off < 256; off <<= 1) {
    int u = (t >= off) ? s[t - off] : 0;
    __syncthreads();
    s[t] += u;
    __syncthreads();
  }
  int texc = s[t] - v;
  int boff = bsum[b];
#pragma unroll
  for (int j = 0; j < 4; j++) {
    int i = base + j;
    if (i < n) row_ptr[i] = boff + texc + loc[j];
  }
  if (b == 0 && t == 0) row_ptr[n] = ne;
}

// Bucket edges by dst: csr_src[row_ptr[d] + cnt[d]++] = src
__global__ void fill_kernel(const int* __restrict__ src, const int* __restrict__ dst,
                            const int* __restrict__ row_ptr, int* cnt,
                            int* __restrict__ csr_src, int ne) {
  int e = blockIdx.x * blockDim.x + threadIdx.x;
  if (e < ne) {
    int d = dst[e];
    int pos = row_ptr[d] + atomicAdd(&cnt[d], 1);
    csr_src[pos] = src[e];
  }
}

// p2[i] = dinv * [x_i, outdeg_i], dinv = rsqrt(indeg+1)
__global__ void p2_kernel(const float* __restrict__ x, const int* __restrict__ outdeg,
                          const int* __restrict__ indeg, float* __restrict__ p2, int n) {
  int i = blockIdx.x * blockDim.x + threadIdx.x;
  if (i < n) {
    float dinv = rsqrtf((float)indeg[i] + 1.0f);
    p2[2 * i]     = dinv * x[i];
    p2[2 * i + 1] = dinv * (float)outdeg[i];
  }
}

// Fused GCN aggregate (CSR gather, 2-wide) + matmul(2x128) + bias + relu.
// One wave per node.
__global__ __launch_bounds__(256) void gcn_a1_kernel(
    const int* __restrict__ row_ptr, const int* __restrict__ csr_src,
    const float* __restrict__ p2, const int* __restrict__ indeg,
    const float* __restrict__ Wg, const float* __restrict__ bg,
    float* __restrict__ a1, int n) {
  int wid = (blockIdx.x * blockDim.x + threadIdx.x) >> 6;
  int lane = threadIdx.x & 63;
  if (wid >= n) return;
  int beg = row_ptr[wid], end = row_ptr[wid + 1];
  float s0 = 0.0f, s1 = 0.0f;
  for (int k = beg + lane; k < end; k += 64) {
    int s = csr_src[k];
    float2 v = *reinterpret_cast<const float2*>(p2 + 2 * (size_t)s);
    s0 += v.x; s1 += v.y;
  }
#pragma unroll
  for (int off = 1; off < 64; off <<= 1) {
    s0 += __shfl_xor(s0, off, 64);
    s1 += __shfl_xor(s1, off, 64);
  }
  float dinv = rsqrtf((float)indeg[wid] + 1.0f);
  float2 self = *reinterpret_cast<const float2*>(p2 + 2 * (size_t)wid);
  float t0 = dinv * (s0 + self.x);
  float t1 = dinv * (s1 + self.y);
  int c0 = lane, c1 = lane + 64;
  float z0 = fmaf(t0, Wg[c0], fmaf(t1, Wg[NCH + c0], bg[c0]));
  float z1 = fmaf(t0, Wg[c1], fmaf(t1, Wg[NCH + c1], bg[c1]));
  float* row = a1 + (size_t)wid * NCH;
  row[c0] = fmaxf(z0, 0.0f);
  row[c1] = fmaxf(z1, 0.0f);
}

// SAGE neighbor sum via CSR gather: one wave per node, float2 per lane.
// No atomics; a1 (25.6MB) is L3-resident so gathers hit cache.
__global__ __launch_bounds__(256) void sage_gather_kernel(
    const int* __restrict__ row_ptr, const int* __restrict__ csr_src,
    const float* __restrict__ a1, float* __restrict__ aggs, int n) {
  int wid = (blockIdx.x * blockDim.x + threadIdx.x) >> 6;
  int lane = threadIdx.x & 63;
  if (wid >= n) return;
  int beg = row_ptr[wid], end = row_ptr[wid + 1];
  const float2* a1v = reinterpret_cast<const float2*>(a1);
  float ax = 0.0f, ay = 0.0f;
  int k = beg;
  for (; k + 1 < end; k += 2) {  // 2x unroll: two gathers in flight
    int sA = csr_src[k], sB = csr_src[k + 1];
    float2 vA = a1v[(size_t)sA * 64 + lane];
    float2 vB = a1v[(size_t)sB * 64 + lane];
    ax += vA.x + vB.x; ay += vA.y + vB.y;
  }
  if (k < end) {
    int sA = csr_src[k];
    float2 vA = a1v[(size_t)sA * 64 + lane];
    ax += vA.x; ay += vA.y;
  }
  float2 o; o.x = ax; o.y = ay;
  reinterpret_cast<float2*>(aggs)[(size_t)wid * 64 + lane] = o;
}

// Fused: a2 = (aggs/cnt)@Wl + b_l + a1@Wr ; v = relu(a2@Wv1+bv1)@Wv2 ; sum.
__global__ __launch_bounds__(256) void head_kernel(
    const float* __restrict__ a1, const float* __restrict__ aggs,
    const int* __restrict__ indeg,
    const float* __restrict__ Wl, const float* __restrict__ bl,
    const float* __restrict__ Wr,
    const float* __restrict__ Wv1, const float* __restrict__ bv1,
    const float* __restrict__ Wv2, float* __restrict__ out, int n) {
  __shared__ float sW[2 * 32 * NCH];
  __shared__ float sIn[2 * TN * 32];
  __shared__ float sA2[TN * NCH];
  int tid = threadIdx.x;
  int node0 = blockIdx.x * TN;
  int c = tid & 127;
  int half = tid >> 7;
  float acc[TN / 2];
  float blc = bl[c];
#pragma unroll
  for (int i = 0; i < TN / 2; i++) acc[i] = blc;

  for (int k0 = 0; k0 < NCH; k0 += 32) {
    for (int t = tid; t < 32 * NCH; t += 256) {
      int kk = t >> 7, cc = t & 127;
      sW[t]            = Wl[(k0 + kk) * NCH + cc];
      sW[32 * NCH + t] = Wr[(k0 + kk) * NCH + cc];
    }
    for (int t = tid; t < TN * 32; t += 256) {
      int nn = t >> 5, kk = t & 31;
      int node = node0 + nn;
      float va = 0.0f, vb = 0.0f;
      if (node < n) {
        float inv = 1.0f / fmaxf((float)indeg[node], 1.0f);
        va = aggs[(size_t)node * NCH + k0 + kk] * inv;
        vb = a1[(size_t)node * NCH + k0 + kk];
      }
      sIn[t]           = va;
      sIn[TN * 32 + t] = vb;
    }
    __syncthreads();
    for (int kk = 0; kk < 32; kk++) {
      float wl = sW[kk * NCH + c];
      float wr = sW[32 * NCH + kk * NCH + c];
#pragma unroll
      for (int i = 0; i < TN / 2; i++) {
        int nn = half + 2 * i;
        acc[i] = fmaf(sIn[nn * 32 + kk], wl, acc[i]);
        acc[i] = fmaf(sIn[TN * 32 + nn * 32 + kk], wr, acc[i]);
      }
    }
    __syncthreads();
  }
#pragma unroll
  for (int i = 0; i < TN / 2; i++) sA2[(half + 2 * i) * NCH + c] = acc[i];
  for (int t = tid; t < NCH * 64; t += 256) sW[t] = Wv1[t];
  __syncthreads();
  int j = tid & 63, w = tid >> 6;
  float bvj = bv1[j], w2 = Wv2[j];
  float vsum = 0.0f;
#pragma unroll
  for (int i = 0; i < TN / 4; i++) {
    int nn = w * (TN / 4) + i;
    if (node0 + nn < n) {
      float h = bvj;
      for (int cc = 0; cc < NCH; cc++)
        h = fmaf(sA2[nn * NCH + cc], sW[cc * 64 + j], h);
      vsum += fmaxf(h, 0.0f) * w2;
    }
  }
#pragma unroll
  for (int off = 32; off > 0; off >>= 1) vsum += __shfl_down(vsum, off, 64);
  if ((tid & 63) == 0) atomicAdd(out, vsum);
}

extern "C" void kernel_launch(void* const* d_in, const int* in_sizes, int n_in,
                              void* d_out, int out_size, void* d_ws, size_t ws_size,
                              hipStream_t stream) {
  const float* x   = (const float*)d_in[0];
  const int*   ei  = (const int*)d_in[1];
  const float* Wg  = (const float*)d_in[2];
  const float* bg  = (const float*)d_in[3];
  const float* Wl  = (const float*)d_in[4];
  const float* bl  = (const float*)d_in[5];
  const float* Wr  = (const float*)d_in[6];
  const float* Wv1 = (const float*)d_in[7];
  const float* bv1 = (const float*)d_in[8];
  const float* Wv2 = (const float*)d_in[9];
  const float* bv2 = (const float*)d_in[10];
  float* out = (float*)d_out;

  int n  = in_sizes[0];
  int E_ = in_sizes[1] / 2;
  const int* src = ei;
  const int* dst = ei + E_;

  // workspace layout
  char* base = (char*)d_ws;
  int*   outdeg  = (int*)base;                    base += (size_t)n * 4;
  int*   indeg   = (int*)base;                    base += (size_t)n * 4;
  int*   cnt     = (int*)base;                    base += (size_t)n * 4;
  int*   row_ptr = (int*)base;                    base += ((size_t)n + 1) * 4;
  int*   bsum    = (int*)base;                    base += 64 * 4;
  int*   csr_src = (int*)base;                    base += (size_t)E_ * 4;
  float* p2      = (float*)base;                  base += (size_t)n * 2 * 4;
  float* a1buf   = (float*)base;                  base += (size_t)n * NCH * 4;
  float* aggs    = (float*)base;                  /* += n*NCH*4 */

  long long zt = 3LL * n;  // outdeg, indeg, cnt (contiguous)
  init_kernel<<<(int)((zt + 255) / 256), 256, 0, stream>>>(outdeg, zt, out, bv2, n);
  degree_kernel<<<(E_ + 255) / 256, 256, 0, stream>>>(src, dst, outdeg, indeg, E_);

  int nb = (n + 1023) / 1024;
  scan1_kernel<<<nb, 256, 0, stream>>>(indeg, bsum, n);
  scan2_kernel<<<1, 64, 0, stream>>>(bsum, nb);
  scan3_kernel<<<nb, 256, 0, stream>>>(indeg, bsum, row_ptr, n, E_);
  fill_kernel<<<(E_ + 255) / 256, 256, 0, stream>>>(src, dst, row_ptr, cnt, csr_src, E_);

  p2_kernel<<<(n + 255) / 256, 256, 0, stream>>>(x, outdeg, indeg, p2, n);

  int wave_blocks = (n * 64 + 255) / 256;
  gcn_a1_kernel<<<wave_blocks, 256, 0, stream>>>(row_ptr, csr_src, p2, indeg, Wg, bg, a1buf, n);
  sage_gather_kernel<<<wave_blocks, 256, 0, stream>>>(row_ptr, csr_src, a1buf, aggs, n);

  head_kernel<<<(n + TN - 1) / TN, 256, 0, stream>>>(a1buf, aggs, indeg, Wl, bl, Wr,
                                                     Wv1, bv1, Wv2, out, n);
}

// Round 3
// 519.734 us; speedup vs baseline: 6.3064x; 1.2831x over previous
//
#include <hip/hip_runtime.h>

#define NCH 128
#define HSTRIDE 264  // ushorts per LDS row: 256 + 8 pad (528B, 16B-aligned)

typedef __attribute__((ext_vector_type(8))) short bf16x8;
typedef __attribute__((ext_vector_type(4))) float f32x4;

__device__ inline unsigned short f2bf(float f) {
  unsigned int u = __builtin_bit_cast(unsigned int, f);
  unsigned int r = u + 0x7fffu + ((u >> 16) & 1u);
  return (unsigned short)(r >> 16);
}
__device__ inline float bflo(unsigned int p) {
  return __builtin_bit_cast(float, p << 16);
}
__device__ inline float bfhi(unsigned int p) {
  return __builtin_bit_cast(float, p & 0xffff0000u);
}

// Zero int counters; init out = N * b_v2 (bias folded analytically).
__global__ void init_kernel(int* zi, long long total, float* out,
                            const float* __restrict__ bv2, int n) {
  long long i = (long long)blockIdx.x * blockDim.x + threadIdx.x;
  if (i < total) zi[i] = 0;
  if (i == 0) out[0] = (float)n * bv2[0];
}

__global__ void degree_kernel(const int* __restrict__ src, const int* __restrict__ dst,
                              int* outdeg, int* indeg, int ne) {
  int e = blockIdx.x * blockDim.x + threadIdx.x;
  if (e < ne) {
    atomicAdd(&outdeg[src[e]], 1);
    atomicAdd(&indeg[dst[e]], 1);
  }
}

// ---- 3-kernel exclusive scan of indeg -> row_ptr ----
__global__ void scan1_kernel(const int* __restrict__ indeg, int* bsum, int n) {
  __shared__ int s[256];
  int b = blockIdx.x, t = threadIdx.x;
  int base = b * 1024 + t * 4;
  int v = 0;
#pragma unroll
  for (int j = 0; j < 4; j++) { int i = base + j; if (i < n) v += indeg[i]; }
  s[t] = v; __syncthreads();
  for (int off = 128; off > 0; off >>= 1) {
    if (t < off) s[t] += s[t + off];
    __syncthreads();
  }
  if (t == 0) bsum[b] = s[0];
}

__global__ void scan2_kernel(int* bsum, int nb) {  // 1 wave, nb <= 64
  int l = threadIdx.x;
  int own = (l < nb) ? bsum[l] : 0;
  int v = own;
  for (int off = 1; off < 64; off <<= 1) {
    int u = __shfl_up(v, off, 64);
    if (l >= off) v += u;
  }
  if (l < nb) bsum[l] = v - own;
}

__global__ void scan3_kernel(const int* __restrict__ indeg, const int* __restrict__ bsum,
                             int* row_ptr, int n, int ne) {
  __shared__ int s[256];
  int b = blockIdx.x, t = threadIdx.x;
  int base = b * 1024 + t * 4;
  int loc[4]; int v = 0;
#pragma unroll
  for (int j = 0; j < 4; j++) {
    int i = base + j;
    int d = (i < n) ? indeg[i] : 0;
    loc[j] = v; v += d;
  }
  s[t] = v; __syncthreads();
  for (int off = 1; off < 256; off <<= 1) {
    int u = (t >= off) ? s[t - off] : 0;
    __syncthreads();
    s[t] += u;
    __syncthreads();
  }
  int texc = s[t] - v;
  int boff = bsum[b];
#pragma unroll
  for (int j = 0; j < 4; j++) {
    int i = base + j;
    if (i < n) row_ptr[i] = boff + texc + loc[j];
  }
  if (b == 0 && t == 0) row_ptr[n] = ne;
}

__global__ void fill_kernel(const int* __restrict__ src, const int* __restrict__ dst,
                            const int* __restrict__ row_ptr, int* cnt,
                            int* __restrict__ csr_src, int ne) {
  int e = blockIdx.x * blockDim.x + threadIdx.x;
  if (e < ne) {
    int d = dst[e];
    int pos = row_ptr[d] + atomicAdd(&cnt[d], 1);
    csr_src[pos] = src[e];
  }
}

__global__ void p2_kernel(const float* __restrict__ x, const int* __restrict__ outdeg,
                          const int* __restrict__ indeg, float* __restrict__ p2, int n) {
  int i = blockIdx.x * blockDim.x + threadIdx.x;
  if (i < n) {
    float dinv = rsqrtf((float)indeg[i] + 1.0f);
    p2[2 * i]     = dinv * x[i];
    p2[2 * i + 1] = dinv * (float)outdeg[i];
  }
}

// Pack weights into MFMA B-fragment order as bf16.
// fw1: [Wl;Wr] 256x128 -> t(8) x s(8) x lane(64) x j(8)
// fw2: Wv1 128x64      -> t(4) x s(4) x lane(64) x j(8)
__global__ void prep_w_kernel(const float* __restrict__ Wl, const float* __restrict__ Wr,
                              const float* __restrict__ Wv1,
                              unsigned short* fw1, unsigned short* fw2) {
  int i = blockIdx.x * blockDim.x + threadIdx.x;
  if (i < 32768) {
    int j = i & 7, l = (i >> 3) & 63, s = (i >> 9) & 7, t = i >> 12;
    int k = s * 32 + (l >> 4) * 8 + j;
    int nn = t * 16 + (l & 15);
    float v = (k < 128) ? Wl[k * 128 + nn] : Wr[(k - 128) * 128 + nn];
    fw1[i] = f2bf(v);
  }
  if (i < 8192) {
    int j = i & 7, l = (i >> 3) & 63, s = (i >> 9) & 3, t = i >> 11;
    int k = s * 32 + (l >> 4) * 8 + j;
    int nn = t * 16 + (l & 15);
    fw2[i] = f2bf(Wv1[k * 64 + nn]);
  }
}

// Fused GCN aggregate (CSR gather, 2-wide) + matmul(2x128) + relu -> bf16 a1
// written into hin[node][128:256]. One wave per node; pad nodes get zeros.
__global__ __launch_bounds__(256) void gcn_a1_kernel(
    const int* __restrict__ row_ptr, const int* __restrict__ csr_src,
    const float* __restrict__ p2, const int* __restrict__ indeg,
    const float* __restrict__ Wg, const float* __restrict__ bg,
    unsigned int* __restrict__ hin, int npad, int n) {
  int wid = (blockIdx.x * blockDim.x + threadIdx.x) >> 6;
  int lane = threadIdx.x & 63;
  if (wid >= npad) return;
  if (wid >= n) { hin[(size_t)wid * 128 + 64 + lane] = 0u; return; }
  int beg = row_ptr[wid], end = row_ptr[wid + 1];
  float s0 = 0.0f, s1 = 0.0f;
  for (int k = beg + lane; k < end; k += 64) {
    int s = csr_src[k];
    float2 v = *reinterpret_cast<const float2*>(p2 + 2 * (size_t)s);
    s0 += v.x; s1 += v.y;
  }
#pragma unroll
  for (int off = 1; off < 64; off <<= 1) {
    s0 += __shfl_xor(s0, off, 64);
    s1 += __shfl_xor(s1, off, 64);
  }
  float dinv = rsqrtf((float)indeg[wid] + 1.0f);
  float2 self = *reinterpret_cast<const float2*>(p2 + 2 * (size_t)wid);
  float t0 = dinv * (s0 + self.x);
  float t1 = dinv * (s1 + self.y);
  int c0 = 2 * lane, c1 = 2 * lane + 1;
  float z0 = fmaxf(fmaf(t0, Wg[c0], fmaf(t1, Wg[NCH + c0], bg[c0])), 0.0f);
  float z1 = fmaxf(fmaf(t0, Wg[c1], fmaf(t1, Wg[NCH + c1], bg[c1])), 0.0f);
  hin[(size_t)wid * 128 + 64 + lane] =
      (unsigned int)f2bf(z0) | ((unsigned int)f2bf(z1) << 16);
}

// SAGE mean aggregation via CSR gather of bf16 a1 rows (256B/edge, coalesced),
// fp32 accumulate, write bf16 into hin[node][0:128].
__global__ __launch_bounds__(256) void sage_gather_kernel(
    const int* __restrict__ row_ptr, const int* __restrict__ csr_src,
    unsigned int* __restrict__ hin, int npad, int n) {
  int wid = (blockIdx.x * blockDim.x + threadIdx.x) >> 6;
  int lane = threadIdx.x & 63;
  if (wid >= npad) return;
  if (wid >= n) { hin[(size_t)wid * 128 + lane] = 0u; return; }
  int beg = row_ptr[wid], end = row_ptr[wid + 1];
  float ax = 0.0f, ay = 0.0f;
  int k = beg;
  for (; k + 1 < end; k += 2) {
    int sA = csr_src[k], sB = csr_src[k + 1];
    unsigned int uA = hin[(size_t)sA * 128 + 64 + lane];
    unsigned int uB = hin[(size_t)sB * 128 + 64 + lane];
    ax += bflo(uA) + bflo(uB);
    ay += bfhi(uA) + bfhi(uB);
  }
  if (k < end) {
    unsigned int uA = hin[(size_t)csr_src[k] * 128 + 64 + lane];
    ax += bflo(uA); ay += bfhi(uA);
  }
  int cnt = end - beg;
  float inv = 1.0f / (float)(cnt > 1 ? cnt : 1);
  hin[(size_t)wid * 128 + lane] =
      (unsigned int)f2bf(ax * inv) | ((unsigned int)f2bf(ay * inv) << 16);
}

// MFMA head: a2 = [agg|a1] @ [Wl;Wr] + bl ; v = relu(a2@Wv1+bv1).Wv2 ; sum.
// Block = 4 waves, 64 nodes. Wave w owns output n-tiles {2w, 2w+1} of GEMM1
// and n2-tile w of GEMM2. B fragments in registers (frag-ordered global),
// A staged in LDS with padded stride.
__global__ __launch_bounds__(256) void head_kernel(
    const unsigned short* __restrict__ hin,
    const unsigned short* __restrict__ fw1, const unsigned short* __restrict__ fw2,
    const float* __restrict__ bl, const float* __restrict__ bv1,
    const float* __restrict__ Wv2, float* __restrict__ out, int n) {
  __shared__ __align__(16) unsigned short sA[64 * HSTRIDE];  // 33 KB
  __shared__ float sRed[4];
  int tid = threadIdx.x;
  int lane = tid & 63;
  int w = tid >> 6;
  int m16 = lane & 15;
  int quad = lane >> 4;
  int node0 = blockIdx.x * 64;

  // stage 64 node rows (512B each) into LDS, padded stride
  const uint4* g = reinterpret_cast<const uint4*>(hin + (size_t)node0 * 256);
  for (int c = tid; c < 2048; c += 256) {
    int row = c >> 5, off = c & 31;
    *reinterpret_cast<uint4*>(&sA[row * HSTRIDE + off * 8]) = g[row * 32 + off];
  }

  // B1 fragments: 2 n-tiles x 8 k-steps, 16B coalesced loads
  bf16x8 b1[2][8];
  const bf16x8* f1 = reinterpret_cast<const bf16x8*>(fw1);
#pragma unroll
  for (int p = 0; p < 2; p++)
#pragma unroll
    for (int s = 0; s < 8; s++)
      b1[p][s] = f1[((w * 2 + p) * 8 + s) * 64 + lane];

  f32x4 acc[4][2];
#pragma unroll
  for (int mt = 0; mt < 4; mt++)
#pragma unroll
    for (int p = 0; p < 2; p++) acc[mt][p] = (f32x4)0.0f;

  __syncthreads();

#pragma unroll
  for (int s = 0; s < 8; s++) {
#pragma unroll
    for (int mt = 0; mt < 4; mt++) {
      bf16x8 aF = *reinterpret_cast<const bf16x8*>(
          &sA[(mt * 16 + m16) * HSTRIDE + s * 32 + quad * 8]);
#pragma unroll
      for (int p = 0; p < 2; p++)
        acc[mt][p] = __builtin_amdgcn_mfma_f32_16x16x32_bf16(aF, b1[p][s],
                                                             acc[mt][p], 0, 0, 0);
    }
  }

  // bias, convert a2 -> bf16, store back into sA (reuse)
  float blv[2];
#pragma unroll
  for (int p = 0; p < 2; p++) blv[p] = bl[(w * 2 + p) * 16 + m16];
  __syncthreads();
#pragma unroll
  for (int mt = 0; mt < 4; mt++)
#pragma unroll
    for (int p = 0; p < 2; p++) {
      int col = (w * 2 + p) * 16 + m16;
#pragma unroll
      for (int r = 0; r < 4; r++) {
        int row = mt * 16 + quad * 4 + r;
        sA[row * HSTRIDE + col] = f2bf(acc[mt][p][r] + blv[p]);
      }
    }
  __syncthreads();

  // GEMM2: wave w owns channels [16w,16w+16), K=128
  bf16x8 b2[4];
  const bf16x8* f2 = reinterpret_cast<const bf16x8*>(fw2);
#pragma unroll
  for (int s = 0; s < 4; s++) b2[s] = f2[(w * 4 + s) * 64 + lane];

  f32x4 acc2[4];
#pragma unroll
  for (int mt = 0; mt < 4; mt++) acc2[mt] = (f32x4)0.0f;

#pragma unroll
  for (int s = 0; s < 4; s++) {
#pragma unroll
    for (int mt = 0; mt < 4; mt++) {
      bf16x8 aF = *reinterpret_cast<const bf16x8*>(
          &sA[(mt * 16 + m16) * HSTRIDE + s * 32 + quad * 8]);
      acc2[mt] = __builtin_amdgcn_mfma_f32_16x16x32_bf16(aF, b2[s], acc2[mt], 0, 0, 0);
    }
  }

  int c2 = w * 16 + m16;
  float bvj = bv1[c2], w2 = Wv2[c2];
  float vsum = 0.0f;
#pragma unroll
  for (int mt = 0; mt < 4; mt++)
#pragma unroll
    for (int r = 0; r < 4; r++) {
      int node = node0 + mt * 16 + quad * 4 + r;
      if (node < n) vsum += fmaxf(acc2[mt][r] + bvj, 0.0f) * w2;
    }
#pragma unroll
  for (int off = 1; off < 64; off <<= 1) vsum += __shfl_xor(vsum, off, 64);
  if (lane == 0) sRed[w] = vsum;
  __syncthreads();
  if (tid == 0) atomicAdd(out, sRed[0] + sRed[1] + sRed[2] + sRed[3]);
}

extern "C" void kernel_launch(void* const* d_in, const int* in_sizes, int n_in,
                              void* d_out, int out_size, void* d_ws, size_t ws_size,
                              hipStream_t stream) {
  const float* x   = (const float*)d_in[0];
  const int*   ei  = (const int*)d_in[1];
  const float* Wg  = (const float*)d_in[2];
  const float* bg  = (const float*)d_in[3];
  const float* Wl  = (const float*)d_in[4];
  const float* bl  = (const float*)d_in[5];
  const float* Wr  = (const float*)d_in[6];
  const float* Wv1 = (const float*)d_in[7];
  const float* bv1 = (const float*)d_in[8];
  const float* Wv2 = (const float*)d_in[9];
  const float* bv2 = (const float*)d_in[10];
  float* out = (float*)d_out;

  int n  = in_sizes[0];
  int E_ = in_sizes[1] / 2;
  int npad = ((n + 63) / 64) * 64;
  const int* src = ei;
  const int* dst = ei + E_;

  // workspace layout (keep 16B alignment per region)
  char* base = (char*)d_ws;
  unsigned short* hin = (unsigned short*)base;  base += (size_t)npad * 256 * 2;
  unsigned short* fw1 = (unsigned short*)base;  base += 32768 * 2;
  unsigned short* fw2 = (unsigned short*)base;  base += 8192 * 2;
  float* p2     = (float*)base;                 base += (size_t)n * 2 * 4;
  int*   outdeg = (int*)base;                   base += (size_t)n * 4;
  int*   indeg  = (int*)base;                   base += (size_t)n * 4;
  int*   cnt    = (int*)base;                   base += (size_t)n * 4;
  int*   row_ptr= (int*)base;                   base += ((size_t)n + 16) * 4;
  int*   bsum   = (int*)base;                   base += 64 * 4;
  int*   csr_src= (int*)base;

  long long zt = 3LL * n;  // outdeg, indeg, cnt contiguous
  init_kernel<<<(int)((zt + 255) / 256), 256, 0, stream>>>(outdeg, zt, out, bv2, n);
  degree_kernel<<<(E_ + 255) / 256, 256, 0, stream>>>(src, dst, outdeg, indeg, E_);

  int nb = (n + 1023) / 1024;
  scan1_kernel<<<nb, 256, 0, stream>>>(indeg, bsum, n);
  scan2_kernel<<<1, 64, 0, stream>>>(bsum, nb);
  scan3_kernel<<<nb, 256, 0, stream>>>(indeg, bsum, row_ptr, n, E_);
  fill_kernel<<<(E_ + 255) / 256, 256, 0, stream>>>(src, dst, row_ptr, cnt, csr_src, E_);

  p2_kernel<<<(n + 255) / 256, 256, 0, stream>>>(x, outdeg, indeg, p2, n);
  prep_w_kernel<<<128, 256, 0, stream>>>(Wl, Wr, Wv1, fw1, fw2);

  int wave_blocks = npad / 4;  // npad waves, 4 waves/block
  gcn_a1_kernel<<<wave_blocks, 256, 0, stream>>>(row_ptr, csr_src, p2, indeg, Wg, bg,
                                                 (unsigned int*)hin, npad, n);
  sage_gather_kernel<<<wave_blocks, 256, 0, stream>>>(row_ptr, csr_src,
                                                      (unsigned int*)hin, npad, n);

  head_kernel<<<npad / 64, 256, 0, stream>>>(hin, fw1, fw2, bl, bv1, Wv2, out, n);
}

// Round 4
// 390.804 us; speedup vs baseline: 8.3869x; 1.3299x over previous
//
#include <hip/hip_runtime.h>

#define NCH 128
#define NREP 8       // histogram replication factor
#define HSTRIDE 264  // ushorts per LDS row: 256 + 8 pad (528B, 16B-aligned)

typedef __attribute__((ext_vector_type(8))) short bf16x8;
typedef __attribute__((ext_vector_type(4))) float f32x4;

__device__ inline unsigned short f2bf(float f) {
  unsigned int u = __builtin_bit_cast(unsigned int, f);
  unsigned int r = u + 0x7fffu + ((u >> 16) & 1u);
  return (unsigned short)(r >> 16);
}
__device__ inline float bflo(unsigned int p) {
  return __builtin_bit_cast(float, p << 16);
}
__device__ inline float bfhi(unsigned int p) {
  return __builtin_bit_cast(float, p & 0xffff0000u);
}

// Zero replicated histogram arrays; init out = N * b_v2 (bias folded).
__global__ void init_kernel(int* zi, long long total, float* out,
                            const float* __restrict__ bv2, int n) {
  long long i = (long long)blockIdx.x * blockDim.x + threadIdx.x;
  if (i < total) zi[i] = 0;
  if (i == 0) out[0] = (float)n * bv2[0];
}

// Replicated histograms (copy = blockIdx&7, replicas n apart -> no shared
// cachelines across copies). indeg atomic's return value = edge's rank
// within its (node,copy) bucket -> stored for the atomic-free fill pass.
__global__ void degree_kernel(const int* __restrict__ src, const int* __restrict__ dst,
                              int* outdeg_rep, int* indeg_rep, int* __restrict__ rank,
                              int n, int ne) {
  int e = blockIdx.x * blockDim.x + threadIdx.x;
  if (e < ne) {
    int c = blockIdx.x & (NREP - 1);
    atomicAdd(&outdeg_rep[c * n + src[e]], 1);
    rank[e] = atomicAdd(&indeg_rep[c * n + dst[e]], 1);
  }
}

// Per-node: reduce replicas -> outdeg/indeg totals, exclusive scan of the 8
// indeg copy-counts -> copyoff, and compute p2 = dinv*[x, outdeg].
__global__ void p2c_kernel(const float* __restrict__ x,
                           const int* __restrict__ outdeg_rep,
                           const int* __restrict__ indeg_rep,
                           int* __restrict__ indeg_total, int* __restrict__ copyoff,
                           float* __restrict__ p2, int n) {
  int i = blockIdx.x * blockDim.x + threadIdx.x;
  if (i >= n) return;
  int od = 0, idt = 0;
  int off[NREP];
#pragma unroll
  for (int c = 0; c < NREP; c++) {
    off[c] = idt;
    idt += indeg_rep[c * n + i];
    od  += outdeg_rep[c * n + i];
  }
#pragma unroll
  for (int c = 0; c < NREP; c++) copyoff[(size_t)i * NREP + c] = off[c];
  indeg_total[i] = idt;
  float dinv = rsqrtf((float)idt + 1.0f);
  p2[2 * i]     = dinv * x[i];
  p2[2 * i + 1] = dinv * (float)od;
}

// ---- 3-kernel exclusive scan of indeg_total -> row_ptr ----
__global__ void scan1_kernel(const int* __restrict__ indeg, int* bsum, int n) {
  __shared__ int s[256];
  int b = blockIdx.x, t = threadIdx.x;
  int base = b * 1024 + t * 4;
  int v = 0;
#pragma unroll
  for (int j = 0; j < 4; j++) { int i = base + j; if (i < n) v += indeg[i]; }
  s[t] = v; __syncthreads();
  for (int off = 128; off > 0; off >>= 1) {
    if (t < off) s[t] += s[t + off];
    __syncthreads();
  }
  if (t == 0) bsum[b] = s[0];
}

__global__ void scan2_kernel(int* bsum, int nb) {  // 1 wave, nb <= 64
  int l = threadIdx.x;
  int own = (l < nb) ? bsum[l] : 0;
  int v = own;
  for (int off = 1; off < 64; off <<= 1) {
    int u = __shfl_up(v, off, 64);
    if (l >= off) v += u;
  }
  if (l < nb) bsum[l] = v - own;
}

__global__ void scan3_kernel(const int* __restrict__ indeg, const int* __restrict__ bsum,
                             int* row_ptr, int n, int ne) {
  __shared__ int s[256];
  int b = blockIdx.x, t = threadIdx.x;
  int base = b * 1024 + t * 4;
  int loc[4]; int v = 0;
#pragma unroll
  for (int j = 0; j < 4; j++) {
    int i = base + j;
    int d = (i < n) ? indeg[i] : 0;
    loc[j] = v; v += d;
  }
  s[t] = v; __syncthreads();
  for (int off = 1; off < 256; off <<= 1) {
    int u = (t >= off) ? s[t - off] : 0;
    __syncthreads();
    s[t] += u;
    __syncthreads();
  }
  int texc = s[t] - v;
  int boff = bsum[b];
#pragma unroll
  for (int j = 0; j < 4; j++) {
    int i = base + j;
    if (i < n) row_ptr[i] = boff + texc + loc[j];
  }
  if (b == 0 && t == 0) row_ptr[n] = ne;
}

// Atomic-free CSR fill: position = row_ptr + copy offset + captured rank.
// Must reproduce degree_kernel's copy mapping (blockIdx&7, same grid shape).
__global__ void fill_kernel(const int* __restrict__ src, const int* __restrict__ dst,
                            const int* __restrict__ row_ptr,
                            const int* __restrict__ copyoff, const int* __restrict__ rank,
                            int* __restrict__ csr_src, int ne) {
  int e = blockIdx.x * blockDim.x + threadIdx.x;
  if (e < ne) {
    int c = blockIdx.x & (NREP - 1);
    int d = dst[e];
    int pos = row_ptr[d] + copyoff[(size_t)d * NREP + c] + rank[e];
    csr_src[pos] = src[e];
  }
}

// Pack weights into MFMA B-fragment order as bf16.
__global__ void prep_w_kernel(const float* __restrict__ Wl, const float* __restrict__ Wr,
                              const float* __restrict__ Wv1,
                              unsigned short* fw1, unsigned short* fw2) {
  int i = blockIdx.x * blockDim.x + threadIdx.x;
  if (i < 32768) {
    int j = i & 7, l = (i >> 3) & 63, s = (i >> 9) & 7, t = i >> 12;
    int k = s * 32 + (l >> 4) * 8 + j;
    int nn = t * 16 + (l & 15);
    float v = (k < 128) ? Wl[k * 128 + nn] : Wr[(k - 128) * 128 + nn];
    fw1[i] = f2bf(v);
  }
  if (i < 8192) {
    int j = i & 7, l = (i >> 3) & 63, s = (i >> 9) & 3, t = i >> 11;
    int k = s * 32 + (l >> 4) * 8 + j;
    int nn = t * 16 + (l & 15);
    fw2[i] = f2bf(Wv1[k * 64 + nn]);
  }
}

// Fused GCN aggregate (CSR gather, 2-wide) + matmul(2x128) + relu -> bf16 a1
// written into hin[node][128:256]. One wave per node; pad nodes get zeros.
__global__ __launch_bounds__(256) void gcn_a1_kernel(
    const int* __restrict__ row_ptr, const int* __restrict__ csr_src,
    const float* __restrict__ p2, const int* __restrict__ indeg,
    const float* __restrict__ Wg, const float* __restrict__ bg,
    unsigned int* __restrict__ hin, int npad, int n) {
  int wid = (blockIdx.x * blockDim.x + threadIdx.x) >> 6;
  int lane = threadIdx.x & 63;
  if (wid >= npad) return;
  if (wid >= n) { hin[(size_t)wid * 128 + 64 + lane] = 0u; return; }
  int beg = row_ptr[wid], end = row_ptr[wid + 1];
  float s0 = 0.0f, s1 = 0.0f;
  for (int k = beg + lane; k < end; k += 64) {
    int s = csr_src[k];
    float2 v = *reinterpret_cast<const float2*>(p2 + 2 * (size_t)s);
    s0 += v.x; s1 += v.y;
  }
#pragma unroll
  for (int off = 1; off < 64; off <<= 1) {
    s0 += __shfl_xor(s0, off, 64);
    s1 += __shfl_xor(s1, off, 64);
  }
  float dinv = rsqrtf((float)indeg[wid] + 1.0f);
  float2 self = *reinterpret_cast<const float2*>(p2 + 2 * (size_t)wid);
  float t0 = dinv * (s0 + self.x);
  float t1 = dinv * (s1 + self.y);
  int c0 = 2 * lane, c1 = 2 * lane + 1;
  float z0 = fmaxf(fmaf(t0, Wg[c0], fmaf(t1, Wg[NCH + c0], bg[c0])), 0.0f);
  float z1 = fmaxf(fmaf(t0, Wg[c1], fmaf(t1, Wg[NCH + c1], bg[c1])), 0.0f);
  hin[(size_t)wid * 128 + 64 + lane] =
      (unsigned int)f2bf(z0) | ((unsigned int)f2bf(z1) << 16);
}

// SAGE mean aggregation via CSR gather of bf16 a1 rows (256B/edge, coalesced),
// fp32 accumulate, write bf16 into hin[node][0:128].
__global__ __launch_bounds__(256) void sage_gather_kernel(
    const int* __restrict__ row_ptr, const int* __restrict__ csr_src,
    unsigned int* __restrict__ hin, int npad, int n) {
  int wid = (blockIdx.x * blockDim.x + threadIdx.x) >> 6;
  int lane = threadIdx.x & 63;
  if (wid >= npad) return;
  if (wid >= n) { hin[(size_t)wid * 128 + lane] = 0u; return; }
  int beg = row_ptr[wid], end = row_ptr[wid + 1];
  float ax = 0.0f, ay = 0.0f;
  int k = beg;
  for (; k + 1 < end; k += 2) {
    int sA = csr_src[k], sB = csr_src[k + 1];
    unsigned int uA = hin[(size_t)sA * 128 + 64 + lane];
    unsigned int uB = hin[(size_t)sB * 128 + 64 + lane];
    ax += bflo(uA) + bflo(uB);
    ay += bfhi(uA) + bfhi(uB);
  }
  if (k < end) {
    unsigned int uA = hin[(size_t)csr_src[k] * 128 + 64 + lane];
    ax += bflo(uA); ay += bfhi(uA);
  }
  int cnt = end - beg;
  float inv = 1.0f / (float)(cnt > 1 ? cnt : 1);
  hin[(size_t)wid * 128 + lane] =
      (unsigned int)f2bf(ax * inv) | ((unsigned int)f2bf(ay * inv) << 16);
}

// MFMA head: a2 = [agg|a1] @ [Wl;Wr] + bl ; v = relu(a2@Wv1+bv1).Wv2 ; sum.
__global__ __launch_bounds__(256) void head_kernel(
    const unsigned short* __restrict__ hin,
    const unsigned short* __restrict__ fw1, const unsigned short* __restrict__ fw2,
    const float* __restrict__ bl, const float* __restrict__ bv1,
    const float* __restrict__ Wv2, float* __restrict__ out, int n) {
  __shared__ __align__(16) unsigned short sA[64 * HSTRIDE];  // 33 KB
  __shared__ float sRed[4];
  int tid = threadIdx.x;
  int lane = tid & 63;
  int w = tid >> 6;
  int m16 = lane & 15;
  int quad = lane >> 4;
  int node0 = blockIdx.x * 64;

  const uint4* g = reinterpret_cast<const uint4*>(hin + (size_t)node0 * 256);
  for (int c = tid; c < 2048; c += 256) {
    int row = c >> 5, off = c & 31;
    *reinterpret_cast<uint4*>(&sA[row * HSTRIDE + off * 8]) = g[row * 32 + off];
  }

  bf16x8 b1[2][8];
  const bf16x8* f1 = reinterpret_cast<const bf16x8*>(fw1);
#pragma unroll
  for (int p = 0; p < 2; p++)
#pragma unroll
    for (int s = 0; s < 8; s++)
      b1[p][s] = f1[((w * 2 + p) * 8 + s) * 64 + lane];

  f32x4 acc[4][2];
#pragma unroll
  for (int mt = 0; mt < 4; mt++)
#pragma unroll
    for (int p = 0; p < 2; p++) acc[mt][p] = (f32x4)0.0f;

  __syncthreads();

#pragma unroll
  for (int s = 0; s < 8; s++) {
#pragma unroll
    for (int mt = 0; mt < 4; mt++) {
      bf16x8 aF = *reinterpret_cast<const bf16x8*>(
          &sA[(mt * 16 + m16) * HSTRIDE + s * 32 + quad * 8]);
#pragma unroll
      for (int p = 0; p < 2; p++)
        acc[mt][p] = __builtin_amdgcn_mfma_f32_16x16x32_bf16(aF, b1[p][s],
                                                             acc[mt][p], 0, 0, 0);
    }
  }

  float blv[2];
#pragma unroll
  for (int p = 0; p < 2; p++) blv[p] = bl[(w * 2 + p) * 16 + m16];
  __syncthreads();
#pragma unroll
  for (int mt = 0; mt < 4; mt++)
#pragma unroll
    for (int p = 0; p < 2; p++) {
      int col = (w * 2 + p) * 16 + m16;
#pragma unroll
      for (int r = 0; r < 4; r++) {
        int row = mt * 16 + quad * 4 + r;
        sA[row * HSTRIDE + col] = f2bf(acc[mt][p][r] + blv[p]);
      }
    }
  __syncthreads();

  bf16x8 b2[4];
  const bf16x8* f2 = reinterpret_cast<const bf16x8*>(fw2);
#pragma unroll
  for (int s = 0; s < 4; s++) b2[s] = f2[(w * 4 + s) * 64 + lane];

  f32x4 acc2[4];
#pragma unroll
  for (int mt = 0; mt < 4; mt++) acc2[mt] = (f32x4)0.0f;

#pragma unroll
  for (int s = 0; s < 4; s++) {
#pragma unroll
    for (int mt = 0; mt < 4; mt++) {
      bf16x8 aF = *reinterpret_cast<const bf16x8*>(
          &sA[(mt * 16 + m16) * HSTRIDE + s * 32 + quad * 8]);
      acc2[mt] = __builtin_amdgcn_mfma_f32_16x16x32_bf16(aF, b2[s], acc2[mt], 0, 0, 0);
    }
  }

  int c2 = w * 16 + m16;
  float bvj = bv1[c2], w2 = Wv2[c2];
  float vsum = 0.0f;
#pragma unroll
  for (int mt = 0; mt < 4; mt++)
#pragma unroll
    for (int r = 0; r < 4; r++) {
      int node = node0 + mt * 16 + quad * 4 + r;
      if (node < n) vsum += fmaxf(acc2[mt][r] + bvj, 0.0f) * w2;
    }
#pragma unroll
  for (int off = 1; off < 64; off <<= 1) vsum += __shfl_xor(vsum, off, 64);
  if (lane == 0) sRed[w] = vsum;
  __syncthreads();
  if (tid == 0) atomicAdd(out, sRed[0] + sRed[1] + sRed[2] + sRed[3]);
}

extern "C" void kernel_launch(void* const* d_in, const int* in_sizes, int n_in,
                              void* d_out, int out_size, void* d_ws, size_t ws_size,
                              hipStream_t stream) {
  const float* x   = (const float*)d_in[0];
  const int*   ei  = (const int*)d_in[1];
  const float* Wg  = (const float*)d_in[2];
  const float* bg  = (const float*)d_in[3];
  const float* Wl  = (const float*)d_in[4];
  const float* bl  = (const float*)d_in[5];
  const float* Wr  = (const float*)d_in[6];
  const float* Wv1 = (const float*)d_in[7];
  const float* bv1 = (const float*)d_in[8];
  const float* Wv2 = (const float*)d_in[9];
  const float* bv2 = (const float*)d_in[10];
  float* out = (float*)d_out;

  int n  = in_sizes[0];
  int E_ = in_sizes[1] / 2;
  int npad = ((n + 63) / 64) * 64;
  const int* src = ei;
  const int* dst = ei + E_;

  // workspace layout (16B alignment per region)
  char* base = (char*)d_ws;
  unsigned short* hin = (unsigned short*)base;  base += (size_t)npad * 256 * 2;
  unsigned short* fw1 = (unsigned short*)base;  base += 32768 * 2;
  unsigned short* fw2 = (unsigned short*)base;  base += 8192 * 2;
  float* p2        = (float*)base;              base += (size_t)n * 2 * 4;
  int* outdeg_rep  = (int*)base;                base += (size_t)NREP * n * 4;
  int* indeg_rep   = (int*)base;                base += (size_t)NREP * n * 4;
  int* indeg_total = (int*)base;                base += (size_t)n * 4;
  int* copyoff     = (int*)base;                base += (size_t)NREP * n * 4;
  int* rank        = (int*)base;                base += (size_t)E_ * 4;
  int* row_ptr     = (int*)base;                base += ((size_t)n + 16) * 4;
  int* bsum        = (int*)base;                base += 64 * 4;
  int* csr_src     = (int*)base;

  long long zt = 2LL * NREP * n;  // outdeg_rep + indeg_rep (contiguous)
  init_kernel<<<(int)((zt + 255) / 256), 256, 0, stream>>>(outdeg_rep, zt, out, bv2, n);
  degree_kernel<<<(E_ + 255) / 256, 256, 0, stream>>>(src, dst, outdeg_rep, indeg_rep,
                                                      rank, n, E_);
  p2c_kernel<<<(n + 255) / 256, 256, 0, stream>>>(x, outdeg_rep, indeg_rep,
                                                  indeg_total, copyoff, p2, n);

  int nb = (n + 1023) / 1024;
  scan1_kernel<<<nb, 256, 0, stream>>>(indeg_total, bsum, n);
  scan2_kernel<<<1, 64, 0, stream>>>(bsum, nb);
  scan3_kernel<<<nb, 256, 0, stream>>>(indeg_total, bsum, row_ptr, n, E_);
  fill_kernel<<<(E_ + 255) / 256, 256, 0, stream>>>(src, dst, row_ptr, copyoff, rank,
                                                    csr_src, E_);

  prep_w_kernel<<<128, 256, 0, stream>>>(Wl, Wr, Wv1, fw1, fw2);

  int wave_blocks = npad / 4;
  gcn_a1_kernel<<<wave_blocks, 256, 0, stream>>>(row_ptr, csr_src, p2, indeg_total,
                                                 Wg, bg, (unsigned int*)hin, npad, n);
  sage_gather_kernel<<<wave_blocks, 256, 0, stream>>>(row_ptr, csr_src,
                                                      (unsigned int*)hin, npad, n);

  head_kernel<<<npad / 64, 256, 0, stream>>>(hin, fw1, fw2, bl, bv1, Wv2, out, n);
}

// Round 5
// 361.493 us; speedup vs baseline: 9.0669x; 1.0811x over previous
//
#include <hip/hip_runtime.h>

#define NCH 128
#define NREP 8       // one histogram replica per XCD
#define HSTRIDE 264  // ushorts per LDS row: 256 + 8 pad (528B, 16B-aligned)

typedef __attribute__((ext_vector_type(8))) short bf16x8;
typedef __attribute__((ext_vector_type(4))) float f32x4;

__device__ inline unsigned short f2bf(float f) {
  unsigned int u = __builtin_bit_cast(unsigned int, f);
  unsigned int r = u + 0x7fffu + ((u >> 16) & 1u);
  return (unsigned short)(r >> 16);
}
__device__ inline float bflo(unsigned int p) {
  return __builtin_bit_cast(float, p << 16);
}
__device__ inline float bfhi(unsigned int p) {
  return __builtin_bit_cast(float, p & 0xffff0000u);
}

// Physical XCD id (0..7 on MI355X, wave-uniform). Replicas indexed by this are
// only ever touched by one XCD -> L2-local atomics are coherent by construction.
__device__ inline int xcc_id() {
  int x;
  asm volatile("s_getreg_b32 %0, hwreg(HW_REG_XCC_ID)" : "=s"(x));
  return x & (NREP - 1);
}

// Zero replicated histogram arrays; init out = N * b_v2 (bias folded).
__global__ void init_kernel(int* zi, long long total, float* out,
                            const float* __restrict__ bv2, int n) {
  long long i = (long long)blockIdx.x * blockDim.x + threadIdx.x;
  if (i < total) zi[i] = 0;
  if (i == 0) out[0] = (float)n * bv2[0];
}

// Histograms with XCD-private replicas and WORKGROUP-scope atomics: the RMW
// executes in the local XCD's L2 (no sc1 write-through to the coherent point,
// which was the R4 bottleneck: 3.2M atomics x 32B sector = 100MB HBM writes).
// rank packs (replica id << 28) | within-bucket rank for the atomic-free fill.
__global__ void degree_kernel(const int* __restrict__ src, const int* __restrict__ dst,
                              int* outdeg_rep, int* indeg_rep, int* __restrict__ rank,
                              int n, int ne) {
  int e = blockIdx.x * blockDim.x + threadIdx.x;
  if (e < ne) {
    int c = xcc_id();
    __hip_atomic_fetch_add(&outdeg_rep[c * n + src[e]], 1,
                           __ATOMIC_RELAXED, __HIP_MEMORY_SCOPE_WORKGROUP);
    int r = __hip_atomic_fetch_add(&indeg_rep[c * n + dst[e]], 1,
                                   __ATOMIC_RELAXED, __HIP_MEMORY_SCOPE_WORKGROUP);
    rank[e] = r | (c << 28);
  }
}

// Per-node: reduce replicas -> outdeg/indeg totals, exclusive scan of the 8
// indeg copy-counts -> copyoff, and compute p2 = dinv*[x, outdeg].
__global__ void p2c_kernel(const float* __restrict__ x,
                           const int* __restrict__ outdeg_rep,
                           const int* __restrict__ indeg_rep,
                           int* __restrict__ indeg_total, int* __restrict__ copyoff,
                           float* __restrict__ p2, int n) {
  int i = blockIdx.x * blockDim.x + threadIdx.x;
  if (i >= n) return;
  int od = 0, idt = 0;
  int off[NREP];
#pragma unroll
  for (int c = 0; c < NREP; c++) {
    off[c] = idt;
    idt += indeg_rep[c * n + i];
    od  += outdeg_rep[c * n + i];
  }
#pragma unroll
  for (int c = 0; c < NREP; c++) copyoff[(size_t)i * NREP + c] = off[c];
  indeg_total[i] = idt;
  float dinv = rsqrtf((float)idt + 1.0f);
  p2[2 * i]     = dinv * x[i];
  p2[2 * i + 1] = dinv * (float)od;
}

// ---- 3-kernel exclusive scan of indeg_total -> row_ptr ----
__global__ void scan1_kernel(const int* __restrict__ indeg, int* bsum, int n) {
  __shared__ int s[256];
  int b = blockIdx.x, t = threadIdx.x;
  int base = b * 1024 + t * 4;
  int v = 0;
#pragma unroll
  for (int j = 0; j < 4; j++) { int i = base + j; if (i < n) v += indeg[i]; }
  s[t] = v; __syncthreads();
  for (int off = 128; off > 0; off >>= 1) {
    if (t < off) s[t] += s[t + off];
    __syncthreads();
  }
  if (t == 0) bsum[b] = s[0];
}

__global__ void scan2_kernel(int* bsum, int nb) {  // 1 wave, nb <= 64
  int l = threadIdx.x;
  int own = (l < nb) ? bsum[l] : 0;
  int v = own;
  for (int off = 1; off < 64; off <<= 1) {
    int u = __shfl_up(v, off, 64);
    if (l >= off) v += u;
  }
  if (l < nb) bsum[l] = v - own;
}

__global__ void scan3_kernel(const int* __restrict__ indeg, const int* __restrict__ bsum,
                             int* row_ptr, int n, int ne) {
  __shared__ int s[256];
  int b = blockIdx.x, t = threadIdx.x;
  int base = b * 1024 + t * 4;
  int loc[4]; int v = 0;
#pragma unroll
  for (int j = 0; j < 4; j++) {
    int i = base + j;
    int d = (i < n) ? indeg[i] : 0;
    loc[j] = v; v += d;
  }
  s[t] = v; __syncthreads();
  for (int off = 1; off < 256; off <<= 1) {
    int u = (t >= off) ? s[t - off] : 0;
    __syncthreads();
    s[t] += u;
    __syncthreads();
  }
  int texc = s[t] - v;
  int boff = bsum[b];
#pragma unroll
  for (int j = 0; j < 4; j++) {
    int i = base + j;
    if (i < n) row_ptr[i] = boff + texc + loc[j];
  }
  if (b == 0 && t == 0) row_ptr[n] = ne;
}

// Atomic-free CSR fill: position = row_ptr + replica offset + captured rank.
__global__ void fill_kernel(const int* __restrict__ src, const int* __restrict__ dst,
                            const int* __restrict__ row_ptr,
                            const int* __restrict__ copyoff, const int* __restrict__ rank,
                            int* __restrict__ csr_src, int ne) {
  int e = blockIdx.x * blockDim.x + threadIdx.x;
  if (e < ne) {
    int rw = rank[e];
    int c = (rw >> 28) & (NREP - 1);
    int r = rw & 0x0FFFFFFF;
    int d = dst[e];
    int pos = row_ptr[d] + copyoff[(size_t)d * NREP + c] + r;
    csr_src[pos] = src[e];
  }
}

// Pack weights into MFMA B-fragment order as bf16.
__global__ void prep_w_kernel(const float* __restrict__ Wl, const float* __restrict__ Wr,
                              const float* __restrict__ Wv1,
                              unsigned short* fw1, unsigned short* fw2) {
  int i = blockIdx.x * blockDim.x + threadIdx.x;
  if (i < 32768) {
    int j = i & 7, l = (i >> 3) & 63, s = (i >> 9) & 7, t = i >> 12;
    int k = s * 32 + (l >> 4) * 8 + j;
    int nn = t * 16 + (l & 15);
    float v = (k < 128) ? Wl[k * 128 + nn] : Wr[(k - 128) * 128 + nn];
    fw1[i] = f2bf(v);
  }
  if (i < 8192) {
    int j = i & 7, l = (i >> 3) & 63, s = (i >> 9) & 3, t = i >> 11;
    int k = s * 32 + (l >> 4) * 8 + j;
    int nn = t * 16 + (l & 15);
    fw2[i] = f2bf(Wv1[k * 64 + nn]);
  }
}

// Fused GCN aggregate (CSR gather, 2-wide) + matmul(2x128) + relu -> bf16 a1
// written into hin[node][128:256]. One wave per node; pad nodes get zeros.
__global__ __launch_bounds__(256) void gcn_a1_kernel(
    const int* __restrict__ row_ptr, const int* __restrict__ csr_src,
    const float* __restrict__ p2, const int* __restrict__ indeg,
    const float* __restrict__ Wg, const float* __restrict__ bg,
    unsigned int* __restrict__ hin, int npad, int n) {
  int wid = (blockIdx.x * blockDim.x + threadIdx.x) >> 6;
  int lane = threadIdx.x & 63;
  if (wid >= npad) return;
  if (wid >= n) { hin[(size_t)wid * 128 + 64 + lane] = 0u; return; }
  int beg = row_ptr[wid], end = row_ptr[wid + 1];
  float s0 = 0.0f, s1 = 0.0f;
  for (int k = beg + lane; k < end; k += 64) {
    int s = csr_src[k];
    float2 v = *reinterpret_cast<const float2*>(p2 + 2 * (size_t)s);
    s0 += v.x; s1 += v.y;
  }
#pragma unroll
  for (int off = 1; off < 64; off <<= 1) {
    s0 += __shfl_xor(s0, off, 64);
    s1 += __shfl_xor(s1, off, 64);
  }
  float dinv = rsqrtf((float)indeg[wid] + 1.0f);
  float2 self = *reinterpret_cast<const float2*>(p2 + 2 * (size_t)wid);
  float t0 = dinv * (s0 + self.x);
  float t1 = dinv * (s1 + self.y);
  int c0 = 2 * lane, c1 = 2 * lane + 1;
  float z0 = fmaxf(fmaf(t0, Wg[c0], fmaf(t1, Wg[NCH + c0], bg[c0])), 0.0f);
  float z1 = fmaxf(fmaf(t0, Wg[c1], fmaf(t1, Wg[NCH + c1], bg[c1])), 0.0f);
  hin[(size_t)wid * 128 + 64 + lane] =
      (unsigned int)f2bf(z0) | ((unsigned int)f2bf(z1) << 16);
}

// SAGE mean aggregation via CSR gather of bf16 a1 rows (256B/edge, coalesced),
// fp32 accumulate, 4x unrolled for load ILP, write bf16 into hin[node][0:128].
__global__ __launch_bounds__(256) void sage_gather_kernel(
    const int* __restrict__ row_ptr, const int* __restrict__ csr_src,
    unsigned int* __restrict__ hin, int npad, int n) {
  int wid = (blockIdx.x * blockDim.x + threadIdx.x) >> 6;
  int lane = threadIdx.x & 63;
  if (wid >= npad) return;
  if (wid >= n) { hin[(size_t)wid * 128 + lane] = 0u; return; }
  int beg = row_ptr[wid], end = row_ptr[wid + 1];
  float ax = 0.0f, ay = 0.0f;
  int k = beg;
  for (; k + 3 < end; k += 4) {
    int sA = csr_src[k], sB = csr_src[k + 1], sC = csr_src[k + 2], sD = csr_src[k + 3];
    unsigned int uA = hin[(size_t)sA * 128 + 64 + lane];
    unsigned int uB = hin[(size_t)sB * 128 + 64 + lane];
    unsigned int uC = hin[(size_t)sC * 128 + 64 + lane];
    unsigned int uD = hin[(size_t)sD * 128 + 64 + lane];
    ax += (bflo(uA) + bflo(uB)) + (bflo(uC) + bflo(uD));
    ay += (bfhi(uA) + bfhi(uB)) + (bfhi(uC) + bfhi(uD));
  }
  for (; k < end; k++) {
    unsigned int uA = hin[(size_t)csr_src[k] * 128 + 64 + lane];
    ax += bflo(uA); ay += bfhi(uA);
  }
  int cnt = end - beg;
  float inv = 1.0f / (float)(cnt > 1 ? cnt : 1);
  hin[(size_t)wid * 128 + lane] =
      (unsigned int)f2bf(ax * inv) | ((unsigned int)f2bf(ay * inv) << 16);
}

// MFMA head: a2 = [agg|a1] @ [Wl;Wr] + bl ; v = relu(a2@Wv1+bv1).Wv2 ; sum.
__global__ __launch_bounds__(256) void head_kernel(
    const unsigned short* __restrict__ hin,
    const unsigned short* __restrict__ fw1, const unsigned short* __restrict__ fw2,
    const float* __restrict__ bl, const float* __restrict__ bv1,
    const float* __restrict__ Wv2, float* __restrict__ out, int n) {
  __shared__ __align__(16) unsigned short sA[64 * HSTRIDE];  // 33 KB
  __shared__ float sRed[4];
  int tid = threadIdx.x;
  int lane = tid & 63;
  int w = tid >> 6;
  int m16 = lane & 15;
  int quad = lane >> 4;
  int node0 = blockIdx.x * 64;

  const uint4* g = reinterpret_cast<const uint4*>(hin + (size_t)node0 * 256);
  for (int c = tid; c < 2048; c += 256) {
    int row = c >> 5, off = c & 31;
    *reinterpret_cast<uint4*>(&sA[row * HSTRIDE + off * 8]) = g[row * 32 + off];
  }

  bf16x8 b1[2][8];
  const bf16x8* f1 = reinterpret_cast<const bf16x8*>(fw1);
#pragma unroll
  for (int p = 0; p < 2; p++)
#pragma unroll
    for (int s = 0; s < 8; s++)
      b1[p][s] = f1[((w * 2 + p) * 8 + s) * 64 + lane];

  f32x4 acc[4][2];
#pragma unroll
  for (int mt = 0; mt < 4; mt++)
#pragma unroll
    for (int p = 0; p < 2; p++) acc[mt][p] = (f32x4)0.0f;

  __syncthreads();

#pragma unroll
  for (int s = 0; s < 8; s++) {
#pragma unroll
    for (int mt = 0; mt < 4; mt++) {
      bf16x8 aF = *reinterpret_cast<const bf16x8*>(
          &sA[(mt * 16 + m16) * HSTRIDE + s * 32 + quad * 8]);
#pragma unroll
      for (int p = 0; p < 2; p++)
        acc[mt][p] = __builtin_amdgcn_mfma_f32_16x16x32_bf16(aF, b1[p][s],
                                                             acc[mt][p], 0, 0, 0);
    }
  }

  float blv[2];
#pragma unroll
  for (int p = 0; p < 2; p++) blv[p] = bl[(w * 2 + p) * 16 + m16];
  __syncthreads();
#pragma unroll
  for (int mt = 0; mt < 4; mt++)
#pragma unroll
    for (int p = 0; p < 2; p++) {
      int col = (w * 2 + p) * 16 + m16;
#pragma unroll
      for (int r = 0; r < 4; r++) {
        int row = mt * 16 + quad * 4 + r;
        sA[row * HSTRIDE + col] = f2bf(acc[mt][p][r] + blv[p]);
      }
    }
  __syncthreads();

  bf16x8 b2[4];
  const bf16x8* f2 = reinterpret_cast<const bf16x8*>(fw2);
#pragma unroll
  for (int s = 0; s < 4; s++) b2[s] = f2[(w * 4 + s) * 64 + lane];

  f32x4 acc2[4];
#pragma unroll
  for (int mt = 0; mt < 4; mt++) acc2[mt] = (f32x4)0.0f;

#pragma unroll
  for (int s = 0; s < 4; s++) {
#pragma unroll
    for (int mt = 0; mt < 4; mt++) {
      bf16x8 aF = *reinterpret_cast<const bf16x8*>(
          &sA[(mt * 16 + m16) * HSTRIDE + s * 32 + quad * 8]);
      acc2[mt] = __builtin_amdgcn_mfma_f32_16x16x32_bf16(aF, b2[s], acc2[mt], 0, 0, 0);
    }
  }

  int c2 = w * 16 + m16;
  float bvj = bv1[c2], w2 = Wv2[c2];
  float vsum = 0.0f;
#pragma unroll
  for (int mt = 0; mt < 4; mt++)
#pragma unroll
    for (int r = 0; r < 4; r++) {
      int node = node0 + mt * 16 + quad * 4 + r;
      if (node < n) vsum += fmaxf(acc2[mt][r] + bvj, 0.0f) * w2;
    }
#pragma unroll
  for (int off = 1; off < 64; off <<= 1) vsum += __shfl_xor(vsum, off, 64);
  if (lane == 0) sRed[w] = vsum;
  __syncthreads();
  if (tid == 0) atomicAdd(out, sRed[0] + sRed[1] + sRed[2] + sRed[3]);
}

extern "C" void kernel_launch(void* const* d_in, const int* in_sizes, int n_in,
                              void* d_out, int out_size, void* d_ws, size_t ws_size,
                              hipStream_t stream) {
  const float* x   = (const float*)d_in[0];
  const int*   ei  = (const int*)d_in[1];
  const float* Wg  = (const float*)d_in[2];
  const float* bg  = (const float*)d_in[3];
  const float* Wl  = (const float*)d_in[4];
  const float* bl  = (const float*)d_in[5];
  const float* Wr  = (const float*)d_in[6];
  const float* Wv1 = (const float*)d_in[7];
  const float* bv1 = (const float*)d_in[8];
  const float* Wv2 = (const float*)d_in[9];
  const float* bv2 = (const float*)d_in[10];
  float* out = (float*)d_out;

  int n  = in_sizes[0];
  int E_ = in_sizes[1] / 2;
  int npad = ((n + 63) / 64) * 64;
  const int* src = ei;
  const int* dst = ei + E_;

  // workspace layout (16B alignment per region)
  char* base = (char*)d_ws;
  unsigned short* hin = (unsigned short*)base;  base += (size_t)npad * 256 * 2;
  unsigned short* fw1 = (unsigned short*)base;  base += 32768 * 2;
  unsigned short* fw2 = (unsigned short*)base;  base += 8192 * 2;
  float* p2        = (float*)base;              base += (size_t)n * 2 * 4;
  int* outdeg_rep  = (int*)base;                base += (size_t)NREP * n * 4;
  int* indeg_rep   = (int*)base;                base += (size_t)NREP * n * 4;
  int* indeg_total = (int*)base;                base += (size_t)n * 4;
  int* copyoff     = (int*)base;                base += (size_t)NREP * n * 4;
  int* rank        = (int*)base;                base += (size_t)E_ * 4;
  int* row_ptr     = (int*)base;                base += ((size_t)n + 16) * 4;
  int* bsum        = (int*)base;                base += 64 * 4;
  int* csr_src     = (int*)base;

  long long zt = 2LL * NREP * n;  // outdeg_rep + indeg_rep (contiguous)
  init_kernel<<<(int)((zt + 255) / 256), 256, 0, stream>>>(outdeg_rep, zt, out, bv2, n);
  degree_kernel<<<(E_ + 255) / 256, 256, 0, stream>>>(src, dst, outdeg_rep, indeg_rep,
                                                      rank, n, E_);
  p2c_kernel<<<(n + 255) / 256, 256, 0, stream>>>(x, outdeg_rep, indeg_rep,
                                                  indeg_total, copyoff, p2, n);

  int nb = (n + 1023) / 1024;
  scan1_kernel<<<nb, 256, 0, stream>>>(indeg_total, bsum, n);
  scan2_kernel<<<1, 64, 0, stream>>>(bsum, nb);
  scan3_kernel<<<nb, 256, 0, stream>>>(indeg_total, bsum, row_ptr, n, E_);
  fill_kernel<<<(E_ + 255) / 256, 256, 0, stream>>>(src, dst, row_ptr, copyoff, rank,
                                                    csr_src, E_);

  prep_w_kernel<<<128, 256, 0, stream>>>(Wl, Wr, Wv1, fw1, fw2);

  int wave_blocks = npad / 4;
  gcn_a1_kernel<<<wave_blocks, 256, 0, stream>>>(row_ptr, csr_src, p2, indeg_total,
                                                 Wg, bg, (unsigned int*)hin, npad, n);
  sage_gather_kernel<<<wave_blocks, 256, 0, stream>>>(row_ptr, csr_src,
                                                      (unsigned int*)hin, npad, n);

  head_kernel<<<npad / 64, 256, 0, stream>>>(hin, fw1, fw2, bl, bv1, Wv2, out, n);
}

// Round 6
// 271.061 us; speedup vs baseline: 12.0919x; 1.3336x over previous
//
#include <hip/hip_runtime.h>

#define NCH 128
#define TILE 8192    // edges per block in pass-1 hist/scatter
#define HSTRIDE 264  // ushorts per LDS row: 256 + 8 pad (528B, 16B-aligned)

typedef __attribute__((ext_vector_type(8))) short bf16x8;
typedef __attribute__((ext_vector_type(4))) float f32x4;

__device__ inline unsigned short f2bf(float f) {
  unsigned int u = __builtin_bit_cast(unsigned int, f);
  unsigned int r = u + 0x7fffu + ((u >> 16) & 1u);
  return (unsigned short)(r >> 16);
}
__device__ inline float bflo(unsigned int p) {
  return __builtin_bit_cast(float, p << 16);
}
__device__ inline float bfhi(unsigned int p) {
  return __builtin_bit_cast(float, p & 0xffff0000u);
}

// ---- Pass 1a: per-block 256-bin LDS histograms of dst>>8 and src>>8 ----
__global__ __launch_bounds__(256) void hist_kernel(
    const int* __restrict__ src, const int* __restrict__ dst,
    int* __restrict__ H, int* __restrict__ Hs, int ne) {
  __shared__ int h1[256], h2[256];
  int t = threadIdx.x, b = blockIdx.x;
  h1[t] = 0; h2[t] = 0;
  __syncthreads();
  int base = b * TILE;
  int lim = min(base + TILE, ne);
  for (int i = base + t; i < lim; i += 256) {
    atomicAdd(&h1[((unsigned)dst[i]) >> 8], 1);
    atomicAdd(&h2[((unsigned)src[i]) >> 8], 1);
  }
  __syncthreads();
  H[b * 256 + t]  = h1[t];
  Hs[b * 256 + t] = h2[t];
}

// ---- Pass 1b: one block. Per-bin running offsets across blocks (H becomes
// within-bin block offset), bin totals -> LDS scan -> bucket_start.
// Also inits out = N*b_v2 and row_ptr[n] = ne.
__global__ __launch_bounds__(256) void scan_kernel(
    int* __restrict__ H, int* __restrict__ Hs,
    int* __restrict__ bstart, int* __restrict__ bstart_s,
    int B1, int ne, float* out, const float* __restrict__ bv2,
    int* __restrict__ row_ptr, int n) {
  __shared__ int sc[256];
  int t = threadIdx.x;
#pragma unroll
  for (int a = 0; a < 2; a++) {
    int* Hm = a ? Hs : H;
    int run = 0;
    for (int blk = 0; blk < B1; blk += 8) {
      int v[8];
#pragma unroll
      for (int j = 0; j < 8; j++)
        v[j] = (blk + j < B1) ? Hm[(blk + j) * 256 + t] : 0;
#pragma unroll
      for (int j = 0; j < 8; j++) {
        if (blk + j < B1) Hm[(blk + j) * 256 + t] = run;
        run += v[j];
      }
    }
    sc[t] = run;
    __syncthreads();
    for (int off = 1; off < 256; off <<= 1) {
      int u = (t >= off) ? sc[t - off] : 0;
      __syncthreads();
      sc[t] += u;
      __syncthreads();
    }
    int excl = sc[t] - run;
    if (a == 0) { bstart[t] = excl; if (t == 0) bstart[256] = ne; }
    else        { bstart_s[t] = excl; if (t == 0) bstart_s[256] = ne; }
    __syncthreads();
  }
  if (t == 0) { out[0] = (float)n * bv2[0]; row_ptr[n] = ne; }
}

// ---- Pass 1c: scatter into coarse buckets via LDS counters (no gl atomics).
// part   : u32 (dst<<16)|src partitioned by dst>>8
// part_s : u16 src partitioned by src>>8
__global__ __launch_bounds__(256) void scatter_kernel(
    const int* __restrict__ src, const int* __restrict__ dst,
    const int* __restrict__ H, const int* __restrict__ Hs,
    const int* __restrict__ bstart, const int* __restrict__ bstart_s,
    unsigned int* __restrict__ part, unsigned short* __restrict__ part_s, int ne) {
  __shared__ int c1[256], c2[256];
  int t = threadIdx.x, b = blockIdx.x;
  c1[t] = H[b * 256 + t] + bstart[t];
  c2[t] = Hs[b * 256 + t] + bstart_s[t];
  __syncthreads();
  int base = b * TILE;
  int lim = min(base + TILE, ne);
  for (int i = base + t; i < lim; i += 256) {
    unsigned d = (unsigned)dst[i], s = (unsigned)src[i];
    int p1 = atomicAdd(&c1[d >> 8], 1);
    part[p1] = (d << 16) | s;
    int p2 = atomicAdd(&c2[s >> 8], 1);
    part_s[p2] = (unsigned short)s;
  }
}

// ---- Pass 2: one block per coarse bucket.
// blockIdx < 256 (dst side): LDS hist of dst&255 == per-node indeg; its scan
//   == row_ptr; then local scatter -> csr_src. blockIdx >= 256 (src side):
//   LDS hist of src&255 -> outdeg.
__global__ __launch_bounds__(256) void bucket_kernel(
    const unsigned int* __restrict__ part, const unsigned short* __restrict__ part_s,
    const int* __restrict__ bstart, const int* __restrict__ bstart_s,
    int* __restrict__ row_ptr, int* __restrict__ csr_src,
    int* __restrict__ outdeg, int n) {
  __shared__ int h[256], sc[256], c[256];
  int t = threadIdx.x;
  int b = blockIdx.x;
  h[t] = 0;
  __syncthreads();
  if (b < 256) {
    int beg = bstart[b], end = bstart[b + 1];
    for (int i = beg + t; i < end; i += 256)
      atomicAdd(&h[(part[i] >> 16) & 255], 1);
    __syncthreads();
    int hv = h[t];
    sc[t] = hv;
    __syncthreads();
    for (int off = 1; off < 256; off <<= 1) {
      int u = (t >= off) ? sc[t - off] : 0;
      __syncthreads();
      sc[t] += u;
      __syncthreads();
    }
    int excl = sc[t] - hv;
    int node = b * 256 + t;
    if (node < n) row_ptr[node] = beg + excl;
    c[t] = beg + excl;
    __syncthreads();
    for (int i = beg + t; i < end; i += 256) {
      unsigned key = part[i];
      int pos = atomicAdd(&c[(key >> 16) & 255], 1);
      csr_src[pos] = (int)(key & 0xFFFFu);
    }
  } else {
    int bs = b - 256;
    int beg = bstart_s[bs], end = bstart_s[bs + 1];
    for (int i = beg + t; i < end; i += 256)
      atomicAdd(&h[part_s[i] & 255], 1);
    __syncthreads();
    int node = bs * 256 + t;
    if (node < n) outdeg[node] = h[t];
  }
}

// p2[i] = dinv * [x_i, outdeg_i], dinv = rsqrt(indeg+1), indeg from row_ptr.
__global__ void p2c_kernel(const float* __restrict__ x, const int* __restrict__ outdeg,
                           const int* __restrict__ row_ptr,
                           float* __restrict__ p2, int n) {
  int i = blockIdx.x * blockDim.x + threadIdx.x;
  if (i >= n) return;
  int idt = row_ptr[i + 1] - row_ptr[i];
  float dinv = rsqrtf((float)idt + 1.0f);
  p2[2 * i]     = dinv * x[i];
  p2[2 * i + 1] = dinv * (float)outdeg[i];
}

// Pack weights into MFMA B-fragment order as bf16.
__global__ void prep_w_kernel(const float* __restrict__ Wl, const float* __restrict__ Wr,
                              const float* __restrict__ Wv1,
                              unsigned short* fw1, unsigned short* fw2) {
  int i = blockIdx.x * blockDim.x + threadIdx.x;
  if (i < 32768) {
    int j = i & 7, l = (i >> 3) & 63, s = (i >> 9) & 7, t = i >> 12;
    int k = s * 32 + (l >> 4) * 8 + j;
    int nn = t * 16 + (l & 15);
    float v = (k < 128) ? Wl[k * 128 + nn] : Wr[(k - 128) * 128 + nn];
    fw1[i] = f2bf(v);
  }
  if (i < 8192) {
    int j = i & 7, l = (i >> 3) & 63, s = (i >> 9) & 3, t = i >> 11;
    int k = s * 32 + (l >> 4) * 8 + j;
    int nn = t * 16 + (l & 15);
    fw2[i] = f2bf(Wv1[k * 64 + nn]);
  }
}

// Fused GCN aggregate (CSR gather, 2-wide) + matmul(2x128) + relu -> bf16 a1
// written into hin[node][128:256]. One wave per node; pad nodes get zeros.
__global__ __launch_bounds__(256) void gcn_a1_kernel(
    const int* __restrict__ row_ptr, const int* __restrict__ csr_src,
    const float* __restrict__ p2,
    const float* __restrict__ Wg, const float* __restrict__ bg,
    unsigned int* __restrict__ hin, int npad, int n) {
  int wid = (blockIdx.x * blockDim.x + threadIdx.x) >> 6;
  int lane = threadIdx.x & 63;
  if (wid >= npad) return;
  if (wid >= n) { hin[(size_t)wid * 128 + 64 + lane] = 0u; return; }
  int beg = row_ptr[wid], end = row_ptr[wid + 1];
  float s0 = 0.0f, s1 = 0.0f;
  for (int k = beg + lane; k < end; k += 64) {
    int s = csr_src[k];
    float2 v = *reinterpret_cast<const float2*>(p2 + 2 * (size_t)s);
    s0 += v.x; s1 += v.y;
  }
#pragma unroll
  for (int off = 1; off < 64; off <<= 1) {
    s0 += __shfl_xor(s0, off, 64);
    s1 += __shfl_xor(s1, off, 64);
  }
  float dinv = rsqrtf((float)(end - beg) + 1.0f);
  float2 self = *reinterpret_cast<const float2*>(p2 + 2 * (size_t)wid);
  float t0 = dinv * (s0 + self.x);
  float t1 = dinv * (s1 + self.y);
  int c0 = 2 * lane, c1 = 2 * lane + 1;
  float z0 = fmaxf(fmaf(t0, Wg[c0], fmaf(t1, Wg[NCH + c0], bg[c0])), 0.0f);
  float z1 = fmaxf(fmaf(t0, Wg[c1], fmaf(t1, Wg[NCH + c1], bg[c1])), 0.0f);
  hin[(size_t)wid * 128 + 64 + lane] =
      (unsigned int)f2bf(z0) | ((unsigned int)f2bf(z1) << 16);
}

// SAGE mean aggregation via CSR gather of bf16 a1 rows (256B/edge, coalesced),
// fp32 accumulate, 4x unrolled for load ILP, write bf16 into hin[node][0:128].
__global__ __launch_bounds__(256) void sage_gather_kernel(
    const int* __restrict__ row_ptr, const int* __restrict__ csr_src,
    unsigned int* __restrict__ hin, int npad, int n) {
  int wid = (blockIdx.x * blockDim.x + threadIdx.x) >> 6;
  int lane = threadIdx.x & 63;
  if (wid >= npad) return;
  if (wid >= n) { hin[(size_t)wid * 128 + lane] = 0u; return; }
  int beg = row_ptr[wid], end = row_ptr[wid + 1];
  float ax = 0.0f, ay = 0.0f;
  int k = beg;
  for (; k + 3 < end; k += 4) {
    int sA = csr_src[k], sB = csr_src[k + 1], sC = csr_src[k + 2], sD = csr_src[k + 3];
    unsigned int uA = hin[(size_t)sA * 128 + 64 + lane];
    unsigned int uB = hin[(size_t)sB * 128 + 64 + lane];
    unsigned int uC = hin[(size_t)sC * 128 + 64 + lane];
    unsigned int uD = hin[(size_t)sD * 128 + 64 + lane];
    ax += (bflo(uA) + bflo(uB)) + (bflo(uC) + bflo(uD));
    ay += (bfhi(uA) + bfhi(uB)) + (bfhi(uC) + bfhi(uD));
  }
  for (; k < end; k++) {
    unsigned int uA = hin[(size_t)csr_src[k] * 128 + 64 + lane];
    ax += bflo(uA); ay += bfhi(uA);
  }
  int cnt = end - beg;
  float inv = 1.0f / (float)(cnt > 1 ? cnt : 1);
  hin[(size_t)wid * 128 + lane] =
      (unsigned int)f2bf(ax * inv) | ((unsigned int)f2bf(ay * inv) << 16);
}

// MFMA head: a2 = [agg|a1] @ [Wl;Wr] + bl ; v = relu(a2@Wv1+bv1).Wv2 ; sum.
__global__ __launch_bounds__(256) void head_kernel(
    const unsigned short* __restrict__ hin,
    const unsigned short* __restrict__ fw1, const unsigned short* __restrict__ fw2,
    const float* __restrict__ bl, const float* __restrict__ bv1,
    const float* __restrict__ Wv2, float* __restrict__ out, int n) {
  __shared__ __align__(16) unsigned short sA[64 * HSTRIDE];  // 33 KB
  __shared__ float sRed[4];
  int tid = threadIdx.x;
  int lane = tid & 63;
  int w = tid >> 6;
  int m16 = lane & 15;
  int quad = lane >> 4;
  int node0 = blockIdx.x * 64;

  const uint4* g = reinterpret_cast<const uint4*>(hin + (size_t)node0 * 256);
  for (int c = tid; c < 2048; c += 256) {
    int row = c >> 5, off = c & 31;
    *reinterpret_cast<uint4*>(&sA[row * HSTRIDE + off * 8]) = g[row * 32 + off];
  }

  bf16x8 b1[2][8];
  const bf16x8* f1 = reinterpret_cast<const bf16x8*>(fw1);
#pragma unroll
  for (int p = 0; p < 2; p++)
#pragma unroll
    for (int s = 0; s < 8; s++)
      b1[p][s] = f1[((w * 2 + p) * 8 + s) * 64 + lane];

  f32x4 acc[4][2];
#pragma unroll
  for (int mt = 0; mt < 4; mt++)
#pragma unroll
    for (int p = 0; p < 2; p++) acc[mt][p] = (f32x4)0.0f;

  __syncthreads();

#pragma unroll
  for (int s = 0; s < 8; s++) {
#pragma unroll
    for (int mt = 0; mt < 4; mt++) {
      bf16x8 aF = *reinterpret_cast<const bf16x8*>(
          &sA[(mt * 16 + m16) * HSTRIDE + s * 32 + quad * 8]);
#pragma unroll
      for (int p = 0; p < 2; p++)
        acc[mt][p] = __builtin_amdgcn_mfma_f32_16x16x32_bf16(aF, b1[p][s],
                                                             acc[mt][p], 0, 0, 0);
    }
  }

  float blv[2];
#pragma unroll
  for (int p = 0; p < 2; p++) blv[p] = bl[(w * 2 + p) * 16 + m16];
  __syncthreads();
#pragma unroll
  for (int mt = 0; mt < 4; mt++)
#pragma unroll
    for (int p = 0; p < 2; p++) {
      int col = (w * 2 + p) * 16 + m16;
#pragma unroll
      for (int r = 0; r < 4; r++) {
        int row = mt * 16 + quad * 4 + r;
        sA[row * HSTRIDE + col] = f2bf(acc[mt][p][r] + blv[p]);
      }
    }
  __syncthreads();

  bf16x8 b2[4];
  const bf16x8* f2 = reinterpret_cast<const bf16x8*>(fw2);
#pragma unroll
  for (int s = 0; s < 4; s++) b2[s] = f2[(w * 4 + s) * 64 + lane];

  f32x4 acc2[4];
#pragma unroll
  for (int mt = 0; mt < 4; mt++) acc2[mt] = (f32x4)0.0f;

#pragma unroll
  for (int s = 0; s < 4; s++) {
#pragma unroll
    for (int mt = 0; mt < 4; mt++) {
      bf16x8 aF = *reinterpret_cast<const bf16x8*>(
          &sA[(mt * 16 + m16) * HSTRIDE + s * 32 + quad * 8]);
      acc2[mt] = __builtin_amdgcn_mfma_f32_16x16x32_bf16(aF, b2[s], acc2[mt], 0, 0, 0);
    }
  }

  int c2 = w * 16 + m16;
  float bvj = bv1[c2], w2 = Wv2[c2];
  float vsum = 0.0f;
#pragma unroll
  for (int mt = 0; mt < 4; mt++)
#pragma unroll
    for (int r = 0; r < 4; r++) {
      int node = node0 + mt * 16 + quad * 4 + r;
      if (node < n) vsum += fmaxf(acc2[mt][r] + bvj, 0.0f) * w2;
    }
#pragma unroll
  for (int off = 1; off < 64; off <<= 1) vsum += __shfl_xor(vsum, off, 64);
  if (lane == 0) sRed[w] = vsum;
  __syncthreads();
  if (tid == 0) atomicAdd(out, sRed[0] + sRed[1] + sRed[2] + sRed[3]);
}

extern "C" void kernel_launch(void* const* d_in, const int* in_sizes, int n_in,
                              void* d_out, int out_size, void* d_ws, size_t ws_size,
                              hipStream_t stream) {
  const float* x   = (const float*)d_in[0];
  const int*   ei  = (const int*)d_in[1];
  const float* Wg  = (const float*)d_in[2];
  const float* bg  = (const float*)d_in[3];
  const float* Wl  = (const float*)d_in[4];
  const float* bl  = (const float*)d_in[5];
  const float* Wr  = (const float*)d_in[6];
  const float* Wv1 = (const float*)d_in[7];
  const float* bv1 = (const float*)d_in[8];
  const float* Wv2 = (const float*)d_in[9];
  const float* bv2 = (const float*)d_in[10];
  float* out = (float*)d_out;

  int n  = in_sizes[0];
  int E_ = in_sizes[1] / 2;
  int npad = ((n + 63) / 64) * 64;
  int B1 = (E_ + TILE - 1) / TILE;
  const int* src = ei;
  const int* dst = ei + E_;

  // workspace layout (16B alignment per region)
  char* base = (char*)d_ws;
  unsigned short* hin = (unsigned short*)base;  base += (size_t)npad * 256 * 2;
  unsigned short* fw1 = (unsigned short*)base;  base += 32768 * 2;
  unsigned short* fw2 = (unsigned short*)base;  base += 8192 * 2;
  float* p2       = (float*)base;               base += (size_t)n * 2 * 4;
  int* H          = (int*)base;                 base += (size_t)B1 * 256 * 4;
  int* Hs         = (int*)base;                 base += (size_t)B1 * 256 * 4;
  int* bstart     = (int*)base;                 base += 260 * 4;
  int* bstart_s   = (int*)base;                 base += 260 * 4;
  unsigned int* part = (unsigned int*)base;     base += (size_t)E_ * 4;
  int* row_ptr    = (int*)base;                 base += ((size_t)n + 16) * 4;
  int* outdeg     = (int*)base;                 base += (size_t)n * 4;
  int* csr_src    = (int*)base;                 base += (size_t)E_ * 4;
  unsigned short* part_s = (unsigned short*)base;

  hist_kernel<<<B1, 256, 0, stream>>>(src, dst, H, Hs, E_);
  scan_kernel<<<1, 256, 0, stream>>>(H, Hs, bstart, bstart_s, B1, E_,
                                     out, bv2, row_ptr, n);
  scatter_kernel<<<B1, 256, 0, stream>>>(src, dst, H, Hs, bstart, bstart_s,
                                         part, part_s, E_);
  bucket_kernel<<<512, 256, 0, stream>>>(part, part_s, bstart, bstart_s,
                                         row_ptr, csr_src, outdeg, n);
  p2c_kernel<<<(n + 255) / 256, 256, 0, stream>>>(x, outdeg, row_ptr, p2, n);
  prep_w_kernel<<<128, 256, 0, stream>>>(Wl, Wr, Wv1, fw1, fw2);

  int wave_blocks = npad / 4;
  gcn_a1_kernel<<<wave_blocks, 256, 0, stream>>>(row_ptr, csr_src, p2,
                                                 Wg, bg, (unsigned int*)hin, npad, n);
  sage_gather_kernel<<<wave_blocks, 256, 0, stream>>>(row_ptr, csr_src,
                                                      (unsigned int*)hin, npad, n);

  head_kernel<<<npad / 64, 256, 0, stream>>>(hin, fw1, fw2, bl, bv1, Wv2, out, n);
}